// Round 8
// baseline (274.109 us; speedup 1.0000x reference)
//
#include <hip/hip_runtime.h>

// WaveCell: y = denom * (2/dt^2 * y1 - (1/dt^2 - b/dt) * y2 + c^2 * lap(y1))
// denom = 1 / (1/dt^2 + b/dt); lap = 5-point stencil with zero padding, / h^2.
// Outputs: (y, y1) concatenated flat in d_out.
//
// R8: stream-isolation split. Hypothesis: 6 interleaved linear streams per
//     TCC channel cap us at ~4.6 TB/s (copy with 2 streams hits 6.3).
//     Kernel B = pure copy y1->out_y1 (NT load+store, 2 streams), runs
//     first (leaves y1 L3-warm). Kernel A = compute-only (y1,y2,c,b ->
//     out_y; 4 streams, c/b L3-resident). Per-kernel rocprof rows will
//     show whether L3 serves A's y1 re-read.

#define WAVE_DT 0.001f
#define WAVE_H  10.0f

typedef float fvec4 __attribute__((ext_vector_type(4)));

// ---------------- Kernel B: y1 -> out_y1 copy ----------------
__global__ __launch_bounds__(256) void WaveCell_copy_kernel(
    const float* __restrict__ src, float* __restrict__ dst, long n4)
{
    long idx    = (long)blockIdx.x * blockDim.x + threadIdx.x;
    const long stride = (long)gridDim.x * blockDim.x;
    for (; idx < n4; idx += stride) {
        const fvec4 v = __builtin_nontemporal_load((const fvec4*)src + idx);
        __builtin_nontemporal_store(v, (fvec4*)dst + idx);
    }
}

// ---------------- Kernel A: compute out_y only ----------------
__global__ __launch_bounds__(256) void WaveCell_790273982844_kernel(
    const float* __restrict__ c,
    const float* __restrict__ b,
    const float* __restrict__ y1,
    const float* __restrict__ y2,
    float* __restrict__ out_y)
{
    constexpr int W  = 4096;
    constexpr int H  = 4096;
    constexpr int W4 = W / 4;            // 1024 float4 per row
    constexpr int HP = H / 2;            // 2048 row-pairs per image

    const float inv_dt2 = 1.0f / (WAVE_DT * WAVE_DT);  // 1e6
    const float inv_dt  = 1.0f / WAVE_DT;              // 1e3
    const float inv_h2  = 1.0f / (WAVE_H * WAVE_H);    // 0.01

    // XCD-contiguous bijective swizzle (nwg = 32768, divisible by 8).
    const unsigned nwg = gridDim.x;
    const unsigned cpx = nwg >> 3;
    const unsigned bid = blockIdx.x;
    const unsigned swz = (bid & 7u) * cpx + (bid >> 3);

    const long t       = (long)swz * blockDim.x + threadIdx.x;
    const int  j4      = (int)(t & (W4 - 1));
    const long pairIdx = t >> 10;                    // 0 .. B*HP-1
    const int  ip      = (int)(pairIdx & (HP - 1));  // pair within image
    const long batch   = pairIdx >> 11;              // HP = 2048 -> shift 11
    const int  i       = ip << 1;                    // even row
    const int  j       = j4 << 2;

    const long base = (batch * H + i) * (long)W;     // flat index of row i
    const float* r0 = y1 + base;                     // y1 row i
    const float* r1 = r0 + W;                        // y1 row i+1
    const float* q0 = y2 + base;                     // y2 row i
    const float* c0 = c + (long)i * W;               // c row i
    const float* b0 = b + (long)i * W;               // b row i

    const fvec4 zero = (fvec4)0.0f;
    const fvec4 ym1 = (i > 0)     ? *(const fvec4*)(r0 - W + j) : zero;
    const fvec4 v0  = *(const fvec4*)(r0 + j);
    const fvec4 v1  = *(const fvec4*)(r1 + j);
    const fvec4 yp2 = (i + 2 < H) ? *(const fvec4*)(r1 + W + j) : zero;

    const float lf0 = (j > 0)     ? r0[j - 1] : 0.0f;
    const float rt0 = (j + 4 < W) ? r0[j + 4] : 0.0f;
    const float lf1 = (j > 0)     ? r1[j - 1] : 0.0f;
    const float rt1 = (j + 4 < W) ? r1[j + 4] : 0.0f;

    const fvec4 cc0 = *(const fvec4*)(c0 + j);
    const fvec4 cc1 = *(const fvec4*)(c0 + W + j);
    const fvec4 bb0 = *(const fvec4*)(b0 + j);
    const fvec4 bb1 = *(const fvec4*)(b0 + W + j);
    const fvec4 p20 = *(const fvec4*)(q0 + j);
    const fvec4 p21 = *(const fvec4*)(q0 + W + j);

    const float le0[4] = {lf0, v0.x, v0.y, v0.z};
    const float re0[4] = {v0.y, v0.z, v0.w, rt0};
    const float le1[4] = {lf1, v1.x, v1.y, v1.z};
    const float re1[4] = {v1.y, v1.z, v1.w, rt1};

    fvec4 yo0, yo1;
#pragma unroll
    for (int k = 0; k < 4; ++k) {
        // row i
        {
            const float lap   = (ym1[k] + v1[k] + le0[k] + re0[k] - 4.0f * v0[k]) * inv_h2;
            const float bdt   = bb0[k] * inv_dt;
            const float denom = __builtin_amdgcn_rcpf(inv_dt2 + bdt);
            yo0[k] = denom * (2.0f * inv_dt2 * v0[k]
                              - (inv_dt2 - bdt) * p20[k]
                              + cc0[k] * cc0[k] * lap);
        }
        // row i+1
        {
            const float lap   = (v0[k] + yp2[k] + le1[k] + re1[k] - 4.0f * v1[k]) * inv_h2;
            const float bdt   = bb1[k] * inv_dt;
            const float denom = __builtin_amdgcn_rcpf(inv_dt2 + bdt);
            yo1[k] = denom * (2.0f * inv_dt2 * v1[k]
                              - (inv_dt2 - bdt) * p21[k]
                              + cc1[k] * cc1[k] * lap);
        }
    }

    float* o0 = out_y + base + j;
    __builtin_nontemporal_store(yo0, (fvec4*)o0);
    __builtin_nontemporal_store(yo1, (fvec4*)(o0 + W));
}

extern "C" void kernel_launch(void* const* d_in, const int* in_sizes, int n_in,
                              void* d_out, int out_size, void* d_ws, size_t ws_size,
                              hipStream_t stream) {
    (void)in_sizes; (void)n_in; (void)d_ws; (void)ws_size; (void)out_size;

    const float* c  = (const float*)d_in[0];
    const float* b  = (const float*)d_in[1];
    const float* y1 = (const float*)d_in[2];
    const float* y2 = (const float*)d_in[3];

    const long B = 4, H = 4096, W = 4096;
    const long N = B * H * W;                 // 67,108,864 elements per field

    float* out_y  = (float*)d_out;
    float* out_y1 = out_y + N;

    // Kernel B: pure copy y1 -> out_y1 (runs first, warms L3 with y1).
    WaveCell_copy_kernel<<<8192, 256, 0, stream>>>(y1, out_y1, N / 4);

    // Kernel A: compute out_y only.
    const long totalThreads = N / 8;          // one (2-row x float4) tile per thread
    const int  block = 256;
    const long grid  = totalThreads / block;  // 32768

    WaveCell_790273982844_kernel<<<(unsigned)grid, block, 0, stream>>>(
        c, b, y1, y2, out_y);
}

// Round 9
// 243.393 us; speedup vs baseline: 1.1262x; 1.1262x over previous
//
#include <hip/hip_runtime.h>

// WaveCell: y = denom * (2/dt^2 * y1 - (1/dt^2 - b/dt) * y2 + c^2 * lap(y1))
// denom = 1 / (1/dt^2 + b/dt); lap = 5-point stencil with zero padding, / h^2.
// Outputs: (y, y1) concatenated flat in d_out.
//
// R9: batch-coarsening. c/b are shared across B=4: one thread handles the
//     same (row, 4-col) tile for ALL 4 batches, loading c/b ONCE into
//     registers (logical c/b traffic 512->128 MB; R3's FETCH=664 showed
//     ~one full c+b re-fetch with normal loads). Keeps fused single kernel,
//     XCD-contiguous bijective swizzle, normal loads, NT stores.

#define WAVE_DT 0.001f
#define WAVE_H  10.0f

typedef float fvec4 __attribute__((ext_vector_type(4)));

__global__ __launch_bounds__(256, 4) void WaveCell_790273982844_kernel(
    const float* __restrict__ c,
    const float* __restrict__ b,
    const float* __restrict__ y1,
    const float* __restrict__ y2,
    float* __restrict__ out_y,
    float* __restrict__ out_y1)
{
    constexpr int  W   = 4096;
    constexpr int  H   = 4096;
    constexpr int  W4  = W / 4;          // 1024 float4 per row
    constexpr long IMG = (long)H * W;    // elements per batch image

    const float inv_dt2 = 1.0f / (WAVE_DT * WAVE_DT);  // 1e6
    const float inv_dt  = 1.0f / WAVE_DT;              // 1e3
    const float inv_h2  = 1.0f / (WAVE_H * WAVE_H);    // 0.01

    // XCD-contiguous bijective swizzle (nwg = 16384, divisible by 8).
    const unsigned nwg = gridDim.x;
    const unsigned cpx = nwg >> 3;
    const unsigned bid = blockIdx.x;
    const unsigned swz = (bid & 7u) * cpx + (bid >> 3);

    const long t  = (long)swz * blockDim.x + threadIdx.x;  // 0 .. H*W4-1
    const int  j4 = (int)(t & (W4 - 1));
    const int  i  = (int)(t >> 10);                        // row 0..H-1
    const int  j  = j4 << 2;

    const long rbase = (long)i * W + j;                    // within-image offset

    // --- shared across batches: c, b (loaded once, reused 4x) ---
    const fvec4 cc = *(const fvec4*)(c + rbase);
    const fvec4 bv = *(const fvec4*)(b + rbase);

    fvec4 bdt, denom;
#pragma unroll
    for (int k = 0; k < 4; ++k) {
        bdt[k]   = bv[k] * inv_dt;
        denom[k] = __builtin_amdgcn_rcpf(inv_dt2 + bdt[k]);
    }

    const bool hasUp = (i > 0);
    const bool hasDn = (i < H - 1);
    const bool hasLf = (j > 0);
    const bool hasRt = (j + 4 < W);

    const fvec4 zero = (fvec4)0.0f;

    // --- per-batch loads, all issued up-front for MLP ---
    fvec4 ce[4], up[4], dn[4], p2[4];
    float lf[4], rt[4];
#pragma unroll
    for (int q = 0; q < 4; ++q) {
        const float* r1 = y1 + q * IMG + rbase;
        const float* r2 = y2 + q * IMG + rbase;
        ce[q] = *(const fvec4*)r1;
        up[q] = hasUp ? *(const fvec4*)(r1 - W) : zero;
        dn[q] = hasDn ? *(const fvec4*)(r1 + W) : zero;
        p2[q] = *(const fvec4*)r2;
        lf[q] = hasLf ? r1[-1] : 0.0f;
        rt[q] = hasRt ? r1[4]  : 0.0f;
    }

#pragma unroll
    for (int q = 0; q < 4; ++q) {
        const float le[4] = {lf[q], ce[q].x, ce[q].y, ce[q].z};
        const float re[4] = {ce[q].y, ce[q].z, ce[q].w, rt[q]};

        fvec4 yo;
#pragma unroll
        for (int k = 0; k < 4; ++k) {
            const float lap = (up[q][k] + dn[q][k] + le[k] + re[k]
                               - 4.0f * ce[q][k]) * inv_h2;
            yo[k] = denom[k] * (2.0f * inv_dt2 * ce[q][k]
                                - (inv_dt2 - bdt[k]) * p2[q][k]
                                + cc[k] * cc[k] * lap);
        }

        __builtin_nontemporal_store(yo,    (fvec4*)(out_y  + q * IMG + rbase));
        __builtin_nontemporal_store(ce[q], (fvec4*)(out_y1 + q * IMG + rbase));
    }
}

extern "C" void kernel_launch(void* const* d_in, const int* in_sizes, int n_in,
                              void* d_out, int out_size, void* d_ws, size_t ws_size,
                              hipStream_t stream) {
    (void)in_sizes; (void)n_in; (void)d_ws; (void)ws_size; (void)out_size;

    const float* c  = (const float*)d_in[0];
    const float* b  = (const float*)d_in[1];
    const float* y1 = (const float*)d_in[2];
    const float* y2 = (const float*)d_in[3];

    const long B = 4, H = 4096, W = 4096;
    const long N = B * H * W;                 // 67,108,864 elements per field

    float* out_y  = (float*)d_out;
    float* out_y1 = out_y + N;

    const long totalThreads = H * (W / 4);    // one (row x float4 x 4-batch) tile per thread
    const int  block = 256;
    const long grid  = totalThreads / block;  // 16384

    WaveCell_790273982844_kernel<<<(unsigned)grid, block, 0, stream>>>(
        c, b, y1, y2, out_y, out_y1);
}

// Round 10
// 242.320 us; speedup vs baseline: 1.1312x; 1.0044x over previous
//
#include <hip/hip_runtime.h>

// WaveCell: y = denom * (2/dt^2 * y1 - (1/dt^2 - b/dt) * y2 + c^2 * lap(y1))
// denom = 1 / (1/dt^2 + b/dt); lap = 5-point stencil with zero padding, / h^2.
// Outputs: (y, y1) concatenated flat in d_out.
//
// R10: register-rolling strip walk. Block = (batch, 1024-col strip, 16-row
//      segment); walks rows downward holding y1 rows (i-1,i,i+1) in
//      registers -> each y1 element vector-loaded ONCE (+2 halo rows per
//      16-row segment). Left/right stencil neighbors via __shfl_up/down
//      (global scalar only at wave-edge lanes). Reads become pure forward
//      streams; no L2-halo-retention dependence. Keeps bijective XCD
//      swizzle + NT stores + fast rcp. Batch-adjacent block order for
//      c/b L2 reuse within an XCD.

#define WAVE_DT 0.001f
#define WAVE_H  10.0f

typedef float fvec4 __attribute__((ext_vector_type(4)));

__global__ __launch_bounds__(256) void WaveCell_790273982844_kernel(
    const float* __restrict__ c,
    const float* __restrict__ b,
    const float* __restrict__ y1,
    const float* __restrict__ y2,
    float* __restrict__ out_y,
    float* __restrict__ out_y1)
{
    constexpr int W   = 4096;
    constexpr int H   = 4096;
    constexpr int SEG = 16;              // output rows per block

    const float inv_dt2 = 1.0f / (WAVE_DT * WAVE_DT);  // 1e6
    const float inv_dt  = 1.0f / WAVE_DT;              // 1e3
    const float inv_h2  = 1.0f / (WAVE_H * WAVE_H);    // 0.01

    // XCD-contiguous bijective swizzle (nwg = 4096, divisible by 8).
    const unsigned nwg = gridDim.x;
    const unsigned cpx = nwg >> 3;
    const unsigned bid = blockIdx.x;
    const unsigned swz = (bid & 7u) * cpx + (bid >> 3);

    // swz = (seg*4 + strip)*4 + batch  (batch innermost -> c/b L2 reuse)
    const unsigned batch = swz & 3u;
    const unsigned strip = (swz >> 2) & 3u;
    const unsigned seg   = swz >> 4;                 // 0..255
    const int r0   = (int)seg * SEG;
    const int j    = ((int)strip << 10) + ((int)threadIdx.x << 2);
    const int lane = (int)(threadIdx.x & 63u);

    const long imgOff = (long)batch * H * W;
    const float* y1b = y1 + imgOff;
    const float* y2b = y2 + imgOff;
    float* oyb = out_y  + imgOff;
    float* o1b = out_y1 + imgOff;

    const fvec4 zero = (fvec4)0.0f;

    // prime the rolling registers
    fvec4 rowm = (r0 > 0) ? *(const fvec4*)(y1b + (long)(r0 - 1) * W + j) : zero;
    fvec4 rowc = *(const fvec4*)(y1b + (long)r0 * W + j);

#pragma unroll
    for (int s = 0; s < SEG; ++s) {
        const int  i  = r0 + s;
        const long ro = (long)i * W + j;

        const fvec4 rowp = (i + 1 < H) ? *(const fvec4*)(y1b + ro + W) : zero;
        const fvec4 p2   = *(const fvec4*)(y2b + ro);
        const fvec4 cc   = *(const fvec4*)(c + (long)i * W + j);
        const fvec4 bb   = *(const fvec4*)(b + (long)i * W + j);

        // horizontal neighbors of rowc: cross-lane within the wave,
        // global scalar reload only at wave-edge lanes.
        float lf = __shfl_up(rowc.w, 1);
        float rt = __shfl_down(rowc.x, 1);
        if (lane == 0)  lf = (j > 0)     ? y1b[ro - 1] : 0.0f;
        if (lane == 63) rt = (j + 4 < W) ? y1b[ro + 4] : 0.0f;

        const float le[4] = {lf, rowc.x, rowc.y, rowc.z};
        const float re[4] = {rowc.y, rowc.z, rowc.w, rt};

        fvec4 yo;
#pragma unroll
        for (int k = 0; k < 4; ++k) {
            const float lap   = (rowm[k] + rowp[k] + le[k] + re[k]
                                 - 4.0f * rowc[k]) * inv_h2;
            const float bdt   = bb[k] * inv_dt;
            const float denom = __builtin_amdgcn_rcpf(inv_dt2 + bdt);
            yo[k] = denom * (2.0f * inv_dt2 * rowc[k]
                             - (inv_dt2 - bdt) * p2[k]
                             + cc[k] * cc[k] * lap);
        }

        __builtin_nontemporal_store(yo,   (fvec4*)(oyb + ro));
        __builtin_nontemporal_store(rowc, (fvec4*)(o1b + ro));

        rowm = rowc;
        rowc = rowp;
    }
}

extern "C" void kernel_launch(void* const* d_in, const int* in_sizes, int n_in,
                              void* d_out, int out_size, void* d_ws, size_t ws_size,
                              hipStream_t stream) {
    (void)in_sizes; (void)n_in; (void)d_ws; (void)ws_size; (void)out_size;

    const float* c  = (const float*)d_in[0];
    const float* b  = (const float*)d_in[1];
    const float* y1 = (const float*)d_in[2];
    const float* y2 = (const float*)d_in[3];

    const long B = 4, H = 4096, W = 4096;
    const long N = B * H * W;                 // 67,108,864 elements per field

    float* out_y  = (float*)d_out;
    float* out_y1 = out_y + N;

    // grid = B(4) x strips(4) x segments(H/16 = 256) = 4096 blocks
    const int block = 256;
    const int grid  = (int)(B * 4 * (H / 16));

    WaveCell_790273982844_kernel<<<grid, block, 0, stream>>>(
        c, b, y1, y2, out_y, out_y1);
}

// Round 11
// 235.321 us; speedup vs baseline: 1.1648x; 1.0297x over previous
//
#include <hip/hip_runtime.h>

// WaveCell: y = denom * (2/dt^2 * y1 - (1/dt^2 - b/dt) * y2 + c^2 * lap(y1))
// denom = 1 / (1/dt^2 + b/dt); lap = 5-point stencil with zero padding, / h^2.
// Outputs: (y, y1) concatenated flat in d_out.
//
// FINAL (= R5, best of 10 rounds at 234.2 us ≈ 5.2 TB/s logical):
//   - 2-row vertical coarsening: 4 y1-row loads serve 2 output rows,
//     deep per-thread MLP, 32768 blocks.
//   - Bijective XCD-contiguous block swizzle: row-neighbor blocks share an
//     XCD's L2 for the up/down halo (R2->R3: +17% with NT stores).
//   - NT stores (outputs never re-read), NORMAL loads (NT loads regressed:
//     L2-bypass latency > traffic savings, R4).
//   - IEEE div kept (fast-rcp was neutral, R7; absmax margin unchanged).
// Exonerated/negative in rounds 4-10: NT loads, 4-row tiles, fast rcp,
// normal stores, split kernels, batch-coarsening, register-rolling strips.
// Residual ~29% gap to the 6.3 TB/s copy ceiling is DRAM-level mixed-stream
// efficiency (6 interleaved streams), invariant across all 7 structures.

#define WAVE_DT 0.001f
#define WAVE_H  10.0f

typedef float fvec4 __attribute__((ext_vector_type(4)));

__global__ __launch_bounds__(256) void WaveCell_790273982844_kernel(
    const float* __restrict__ c,
    const float* __restrict__ b,
    const float* __restrict__ y1,
    const float* __restrict__ y2,
    float* __restrict__ out_y,
    float* __restrict__ out_y1)
{
    constexpr int W  = 4096;
    constexpr int H  = 4096;
    constexpr int W4 = W / 4;            // 1024 float4 per row
    constexpr int HP = H / 2;            // 2048 row-pairs per image

    const float inv_dt2 = 1.0f / (WAVE_DT * WAVE_DT);  // 1e6
    const float inv_dt  = 1.0f / WAVE_DT;              // 1e3
    const float inv_h2  = 1.0f / (WAVE_H * WAVE_H);    // 0.01

    // XCD-contiguous bijective swizzle (nwg = 32768, divisible by 8).
    const unsigned nwg = gridDim.x;
    const unsigned cpx = nwg >> 3;
    const unsigned bid = blockIdx.x;
    const unsigned swz = (bid & 7u) * cpx + (bid >> 3);

    const long t       = (long)swz * blockDim.x + threadIdx.x;
    const int  j4      = (int)(t & (W4 - 1));
    const long pairIdx = t >> 10;                    // 0 .. B*HP-1
    const int  ip      = (int)(pairIdx & (HP - 1));  // pair within image
    const long batch   = pairIdx >> 11;              // HP = 2048 -> shift 11
    const int  i       = ip << 1;                    // even row
    const int  j       = j4 << 2;

    const long base = (batch * H + i) * (long)W;     // flat index of row i
    const float* r0 = y1 + base;                     // y1 row i
    const float* r1 = r0 + W;                        // y1 row i+1
    const float* q0 = y2 + base;                     // y2 row i
    const float* c0 = c + (long)i * W;               // c row i
    const float* b0 = b + (long)i * W;               // b row i

    const fvec4 zero = (fvec4)0.0f;
    const fvec4 ym1 = (i > 0)     ? *(const fvec4*)(r0 - W + j) : zero;
    const fvec4 v0  = *(const fvec4*)(r0 + j);
    const fvec4 v1  = *(const fvec4*)(r1 + j);
    const fvec4 yp2 = (i + 2 < H) ? *(const fvec4*)(r1 + W + j) : zero;

    const float lf0 = (j > 0)     ? r0[j - 1] : 0.0f;
    const float rt0 = (j + 4 < W) ? r0[j + 4] : 0.0f;
    const float lf1 = (j > 0)     ? r1[j - 1] : 0.0f;
    const float rt1 = (j + 4 < W) ? r1[j + 4] : 0.0f;

    const fvec4 cc0 = *(const fvec4*)(c0 + j);
    const fvec4 cc1 = *(const fvec4*)(c0 + W + j);
    const fvec4 bb0 = *(const fvec4*)(b0 + j);
    const fvec4 bb1 = *(const fvec4*)(b0 + W + j);
    const fvec4 p20 = *(const fvec4*)(q0 + j);
    const fvec4 p21 = *(const fvec4*)(q0 + W + j);

    const float le0[4] = {lf0, v0.x, v0.y, v0.z};
    const float re0[4] = {v0.y, v0.z, v0.w, rt0};
    const float le1[4] = {lf1, v1.x, v1.y, v1.z};
    const float re1[4] = {v1.y, v1.z, v1.w, rt1};

    fvec4 yo0, yo1;
#pragma unroll
    for (int k = 0; k < 4; ++k) {
        // row i
        {
            const float lap   = (ym1[k] + v1[k] + le0[k] + re0[k] - 4.0f * v0[k]) * inv_h2;
            const float bdt   = bb0[k] * inv_dt;
            const float denom = 1.0f / (inv_dt2 + bdt);
            yo0[k] = denom * (2.0f * inv_dt2 * v0[k]
                              - (inv_dt2 - bdt) * p20[k]
                              + cc0[k] * cc0[k] * lap);
        }
        // row i+1
        {
            const float lap   = (v0[k] + yp2[k] + le1[k] + re1[k] - 4.0f * v1[k]) * inv_h2;
            const float bdt   = bb1[k] * inv_dt;
            const float denom = 1.0f / (inv_dt2 + bdt);
            yo1[k] = denom * (2.0f * inv_dt2 * v1[k]
                              - (inv_dt2 - bdt) * p21[k]
                              + cc1[k] * cc1[k] * lap);
        }
    }

    float* o0 = out_y  + base + j;
    float* o1 = out_y1 + base + j;
    __builtin_nontemporal_store(yo0, (fvec4*)o0);
    __builtin_nontemporal_store(yo1, (fvec4*)(o0 + W));
    __builtin_nontemporal_store(v0,  (fvec4*)o1);
    __builtin_nontemporal_store(v1,  (fvec4*)(o1 + W));
}

extern "C" void kernel_launch(void* const* d_in, const int* in_sizes, int n_in,
                              void* d_out, int out_size, void* d_ws, size_t ws_size,
                              hipStream_t stream) {
    (void)in_sizes; (void)n_in; (void)d_ws; (void)ws_size; (void)out_size;

    const float* c  = (const float*)d_in[0];
    const float* b  = (const float*)d_in[1];
    const float* y1 = (const float*)d_in[2];
    const float* y2 = (const float*)d_in[3];

    const long B = 4, H = 4096, W = 4096;
    const long N = B * H * W;                 // 67,108,864 elements per field

    float* out_y  = (float*)d_out;
    float* out_y1 = out_y + N;

    const long totalThreads = N / 8;          // one (2-row x float4) tile per thread
    const int  block = 256;
    const long grid  = totalThreads / block;  // 32768

    WaveCell_790273982844_kernel<<<(unsigned)grid, block, 0, stream>>>(
        c, b, y1, y2, out_y, out_y1);
}